// Round 1
// baseline (504.893 us; speedup 1.0000x reference)
//
#include <hip/hip_runtime.h>
#include <cmath>

#define DEV __device__ __forceinline__

namespace {

constexpr int Kp    = 127;          // patch tokens
constexpr int Mrows = 32 * Kp;      // 4064 = B*K
constexpr int Rred  = 128 * Kp;     // 16256 = D*K (flat reduction length)

DEV float q88(float x) {
  float r = rintf(x * 256.0f);                       // round half to even, like jnp.round
  r = fminf(fmaxf(r, -32768.0f), 32767.0f);
  return r * 0.00390625f;
}
DEV float sigmoid_(float x) { return 1.0f / (1.0f + expf(-x)); }

DEV void fma16(const float4 av, const float4 bv, float (&acc)[4][4]) {
  acc[0][0] = fmaf(av.x, bv.x, acc[0][0]); acc[0][1] = fmaf(av.x, bv.y, acc[0][1]);
  acc[0][2] = fmaf(av.x, bv.z, acc[0][2]); acc[0][3] = fmaf(av.x, bv.w, acc[0][3]);
  acc[1][0] = fmaf(av.y, bv.x, acc[1][0]); acc[1][1] = fmaf(av.y, bv.y, acc[1][1]);
  acc[1][2] = fmaf(av.y, bv.z, acc[1][2]); acc[1][3] = fmaf(av.y, bv.w, acc[1][3]);
  acc[2][0] = fmaf(av.z, bv.x, acc[2][0]); acc[2][1] = fmaf(av.z, bv.y, acc[2][1]);
  acc[2][2] = fmaf(av.z, bv.z, acc[2][2]); acc[2][3] = fmaf(av.z, bv.w, acc[2][3]);
  acc[3][0] = fmaf(av.w, bv.x, acc[3][0]); acc[3][1] = fmaf(av.w, bv.y, acc[3][1]);
  acc[3][2] = fmaf(av.w, bv.z, acc[3][2]); acc[3][3] = fmaf(av.w, bv.w, acc[3][3]);
}

// ---------------- K0: quantize small weights (and transpose w_patch to [j][c][d]) -------------
__global__ __launch_bounds__(256) void k_quant(
    const float* __restrict__ wproj, const float* __restrict__ bproj,
    const float* __restrict__ wpatch, const float* __restrict__ bpatch,
    const float* __restrict__ whead, const float* __restrict__ bhead,
    const float* __restrict__ bflat,
    float* __restrict__ wq_proj, float* __restrict__ bq_proj, float* __restrict__ wpq,
    float* __restrict__ bq_patch, float* __restrict__ wq_head, float* __restrict__ bq_head,
    float* __restrict__ bq_flat) {
  int i = blockIdx.x * 256 + threadIdx.x;
  if (i < 262144) {
    int j = i >> 14;          // /16384
    int c = (i >> 7) & 127;
    int d = i & 127;
    wpq[i] = q88(wpatch[(d * 128 + c) * 16 + j]);   // w_patch[d][c][j] -> wpq[j][c][d]
  }
  int t = i - 262144;
  if (t >= 0) {
    if      (t < 1024) wq_proj[t]         = q88(wproj[t]);
    else if (t < 1152) bq_proj[t - 1024]  = q88(bproj[t - 1024]);
    else if (t < 1280) bq_patch[t - 1152] = q88(bpatch[t - 1152]);
    else if (t < 1536) wq_head[t - 1280]  = q88(whead[t - 1280]);
    else if (t < 1538) bq_head[t - 1536]  = q88(bhead[t - 1536]);
    else if (t < 4610) bq_flat[t - 1538]  = q88(bflat[t - 1538]);
  }
}

// ---------------- K1: 1x1 conv (proj) -> xpq[b][l][c] (quantized) ----------------------------
__global__ __launch_bounds__(256) void k_proj(const float* __restrict__ x, const float* __restrict__ wq,
                                              const float* __restrict__ bq, float* __restrict__ xpq) {
  int bl0 = blockIdx.x * 16;          // 16 (b,l) rows per block; grid 2048
  int tid = threadIdx.x;
  __shared__ float xs[128];
  if (tid < 128) xs[tid] = q88(x[(size_t)bl0 * 8 + tid]);
  __syncthreads();
  int o = tid & 127;
  int half = tid >> 7;                // 0,1
  float wv[8];
#pragma unroll
  for (int c = 0; c < 8; ++c) wv[c] = wq[o * 8 + c];
  float bb = bq[o];
#pragma unroll
  for (int il = 0; il < 8; ++il) {
    int l_loc = half * 8 + il;
    float acc = bb;
#pragma unroll
    for (int c = 0; c < 8; ++c) acc = fmaf(xs[l_loc * 8 + c], wv[c], acc);
    xpq[(size_t)(bl0 + l_loc) * 128 + o] = q88(acc);
  }
}

// ---------------- K2: patch conv as 16 accumulated GEMMs, j-split x4 -------------------------
__global__ __launch_bounds__(256) void k_patch(const float* __restrict__ xpq, const float* __restrict__ wpq,
                                               float* __restrict__ partJ) {
  __shared__ __align__(16) float As[128][36];
  int mt = blockIdx.x, jg = blockIdx.y;
  int tid = threadIdx.x;
  int mr = tid & 31, c0 = (tid >> 5) * 16;
  int tn = tid & 31, tm8 = tid >> 5;
  int m0 = mt * 32;
  int g = m0 + mr;
  int bb = g / 127, kq = g % 127;
  float acc[4][4] = {};
  for (int jj = 0; jj < 4; ++jj) {
    int j = jg * 4 + jj;
    const float* src = xpq + ((size_t)bb * 1024 + kq * 8 + j) * 128 + c0;
    __syncthreads();
#pragma unroll
    for (int q = 0; q < 4; ++q) {
      float4 v = *reinterpret_cast<const float4*>(src + q * 4);
      As[c0 + q * 4 + 0][mr] = v.x;
      As[c0 + q * 4 + 1][mr] = v.y;
      As[c0 + q * 4 + 2][mr] = v.z;
      As[c0 + q * 4 + 3][mr] = v.w;
    }
    __syncthreads();
    const float* wp = wpq + (size_t)j * 16384 + tn * 4;
#pragma unroll 4
    for (int c = 0; c < 128; ++c) {
      float4 bv = *reinterpret_cast<const float4*>(wp + c * 128);
      float4 av = *reinterpret_cast<const float4*>(&As[c][tm8 * 4]);
      fma16(av, bv, acc);
    }
  }
  float* dst = partJ + ((size_t)jg * Mrows + m0) * 128 + tn * 4;
#pragma unroll
  for (int i = 0; i < 4; ++i) {
    float4 o4 = make_float4(acc[i][0], acc[i][1], acc[i][2], acc[i][3]);
    *reinterpret_cast<float4*>(dst + (size_t)(tm8 * 4 + i) * 128) = o4;
  }
}

// ---------------- K3: combine j-partials + bias, q88, add positional encoding ----------------
__global__ __launch_bounds__(256) void k_combine(const float* __restrict__ partJ, const float* __restrict__ bqp,
                                                 const float* __restrict__ pe, const float* __restrict__ pesc,
                                                 float* __restrict__ h) {
  int i = blockIdx.x * 256 + threadIdx.x;  // < 520192
  int n = i & 127;
  int gq = i >> 7;
  int k = gq % 127;
  float s = partJ[i] + partJ[520192 + i] + partJ[2 * 520192 + i] + partJ[3 * 520192 + i] + bqp[n];
  h[i] = q88(s) + pesc[0] * pe[k * 128 + n];
}

// ---------------- K4: layernorm + (hn @ w_in -> silu -> u) / (hn @ w_gate -> silu -> g) -------
__global__ __launch_bounds__(256) void k_ln_ug(const float* __restrict__ h, const float* __restrict__ lng,
                                               const float* __restrict__ lnb, const float* __restrict__ Win,
                                               const float* __restrict__ Wgate, float* __restrict__ u,
                                               float* __restrict__ gbuf) {
  __shared__ __align__(16) float As[128][36];
  __shared__ float mean_s[32], inv_s[32];
  const float* W = blockIdx.y ? Wgate : Win;
  float* out = blockIdx.y ? gbuf : u;
  int tid = threadIdx.x;
  int mr = tid & 31, c0 = (tid >> 5) * 16;
  int m0 = blockIdx.x * 32;
  const float* src = h + (size_t)(m0 + mr) * 128 + c0;
#pragma unroll
  for (int q = 0; q < 4; ++q) {
    float4 v = *reinterpret_cast<const float4*>(src + q * 4);
    As[c0 + q * 4 + 0][mr] = v.x;
    As[c0 + q * 4 + 1][mr] = v.y;
    As[c0 + q * 4 + 2][mr] = v.z;
    As[c0 + q * 4 + 3][mr] = v.w;
  }
  __syncthreads();
  if (tid < 32) {
    float s = 0.f;
    for (int c = 0; c < 128; ++c) s += As[c][tid];
    float mn = s * (1.0f / 128.0f);
    float s2 = 0.f;
    for (int c = 0; c < 128; ++c) { float dv = As[c][tid] - mn; s2 = fmaf(dv, dv, s2); }
    mean_s[tid] = mn;
    inv_s[tid] = rsqrtf(s2 * (1.0f / 128.0f) + 1e-5f);
  }
  __syncthreads();
  float mnv = mean_s[mr], invv = inv_s[mr];
#pragma unroll
  for (int q = 0; q < 16; ++q) {
    int c = c0 + q;
    As[c][mr] = (As[c][mr] - mnv) * invv * lng[c] + lnb[c];
  }
  __syncthreads();
  int tn = tid & 31, tm8 = tid >> 5;
  float acc[4][4] = {};
  const float* wp = W + tn * 4;
#pragma unroll 4
  for (int c = 0; c < 128; ++c) {
    float4 bv = *reinterpret_cast<const float4*>(wp + c * 128);
    float4 av = *reinterpret_cast<const float4*>(&As[c][tm8 * 4]);
    fma16(av, bv, acc);
  }
  float* dst = out + (size_t)m0 * 128 + tn * 4;
#pragma unroll
  for (int i = 0; i < 4; ++i) {
    float4 o4;
    { float xq = q88(acc[i][0]); o4.x = q88(xq * sigmoid_(xq)); }
    { float xq = q88(acc[i][1]); o4.y = q88(xq * sigmoid_(xq)); }
    { float xq = q88(acc[i][2]); o4.z = q88(xq * sigmoid_(xq)); }
    { float xq = q88(acc[i][3]); o4.w = q88(xq * sigmoid_(xq)); }
    *reinterpret_cast<float4*>(dst + (size_t)(tm8 * 4 + i) * 128) = o4;
  }
}

// ---------------- K5: lambda = q88(sigmoid(q88(u @ w_dt^T + b_dt))) --------------------------
__global__ __launch_bounds__(128) void k_lam(const float* __restrict__ u, const float* __restrict__ wdt,
                                             const float* __restrict__ bdt, float* __restrict__ lam) {
  int blk = blockIdx.x;
  int b = blk / 127, t = blk % 127;
  int d = threadIdx.x;
  __shared__ float wr[127];
  if (d < 127) wr[d] = wdt[t * 127 + d];
  __syncthreads();
  const float* up = u + (size_t)b * (127 * 128) + d;
  float acc = 0.f;
#pragma unroll 4
  for (int k = 0; k < 127; ++k) acc = fmaf(up[(size_t)k * 128], wr[k], acc);
  float pre = q88(acc + bdt[t]);
  lam[((size_t)b * 127 + t) * 128 + d] = q88(sigmoid_(pre));
}

// ---------------- K6: sequential scan, fused with p = y*g (in-place over lam buffer) ---------
__global__ __launch_bounds__(256) void k_scan(const float* __restrict__ u, const float* __restrict__ gbuf,
                                              float* __restrict__ lamp) {
  int gt = blockIdx.x * 256 + threadIdx.x;  // 4096 = B*D
  int b = gt >> 7, d = gt & 127;
  size_t base = (size_t)b * (127 * 128) + d;
  float s = 0.f;
  for (int t = 0; t < 127; ++t) {
    size_t idx = base + (size_t)t * 128;
    float lm = lamp[idx];
    float uu = u[idx];
    s = lm * s + (1.0f - lm) * uu;
    lamp[idx] = s * gbuf[idx];
  }
}

// ---------------- K7: h += p @ w_out --------------------------------------------------------
__global__ __launch_bounds__(256) void k_outproj(const float* __restrict__ p, const float* __restrict__ W,
                                                 float* __restrict__ h) {
  __shared__ __align__(16) float As[128][36];
  int tid = threadIdx.x;
  int mr = tid & 31, c0 = (tid >> 5) * 16;
  int m0 = blockIdx.x * 32;
  const float* src = p + (size_t)(m0 + mr) * 128 + c0;
#pragma unroll
  for (int q = 0; q < 4; ++q) {
    float4 v = *reinterpret_cast<const float4*>(src + q * 4);
    As[c0 + q * 4 + 0][mr] = v.x;
    As[c0 + q * 4 + 1][mr] = v.y;
    As[c0 + q * 4 + 2][mr] = v.z;
    As[c0 + q * 4 + 3][mr] = v.w;
  }
  __syncthreads();
  int tn = tid & 31, tm8 = tid >> 5;
  float acc[4][4] = {};
  const float* wp = W + tn * 4;
#pragma unroll 4
  for (int c = 0; c < 128; ++c) {
    float4 bv = *reinterpret_cast<const float4*>(wp + c * 128);
    float4 av = *reinterpret_cast<const float4*>(&As[c][tm8 * 4]);
    fma16(av, bv, acc);
  }
  float* dst = h + (size_t)m0 * 128 + tn * 4;
#pragma unroll
  for (int i = 0; i < 4; ++i) {
    float4 hv = *reinterpret_cast<float4*>(dst + (size_t)(tm8 * 4 + i) * 128);
    hv.x += acc[i][0]; hv.y += acc[i][1]; hv.z += acc[i][2]; hv.w += acc[i][3];
    *reinterpret_cast<float4*>(dst + (size_t)(tm8 * 4 + i) * 128) = hv;
  }
}

// ---------------- K8: final layernorm + q88 + transpose to [b][d][k] -------------------------
__global__ __launch_bounds__(128) void k_lnf(const float* __restrict__ h, const float* __restrict__ gg,
                                             const float* __restrict__ bb, float* __restrict__ xp2q) {
  int row = blockIdx.x;  // 4064
  int d = threadIdx.x;
  float v = h[(size_t)row * 128 + d];
  __shared__ float red[128];
  __shared__ float mn_s, inv_s;
  red[d] = v;
  __syncthreads();
  for (int off = 64; off > 0; off >>= 1) {
    if (d < off) red[d] += red[d + off];
    __syncthreads();
  }
  if (d == 0) mn_s = red[0] * (1.0f / 128.0f);
  __syncthreads();
  float dv = v - mn_s;
  red[d] = dv * dv;
  __syncthreads();
  for (int off = 64; off > 0; off >>= 1) {
    if (d < off) red[d] += red[d + off];
    __syncthreads();
  }
  if (d == 0) inv_s = rsqrtf(red[0] * (1.0f / 128.0f) + 1e-5f);
  __syncthreads();
  float hn = (v - mn_s) * inv_s * gg[d] + bb[d];
  int b = row / 127, k = row % 127;
  xp2q[((size_t)b * 128 + d) * 127 + k] = q88(hn);
}

// ---------------- K9: flat contraction C[b,o] = sum_r Aq[b,r]*q88(Wf[o,r]), r-split x4 -------
__global__ __launch_bounds__(256) void k_flat(const float* __restrict__ Aq, const float* __restrict__ Wf,
                                              float* __restrict__ partF) {
  __shared__ __align__(16) float As[32][132];
  __shared__ __align__(16) float Ws[32][132];
  int ot = blockIdx.x, rs = blockIdx.y;
  int tid = threadIdx.x;
  int tb = tid & 31, to = tid >> 5;   // b lane, o-group
  int row = tid >> 3;                 // staging row 0..31
  int col0 = (tid & 7) * 16;          // staging col 0..112
  int r0 = rs * 4064;
  float acc[4] = {0.f, 0.f, 0.f, 0.f};
  for (int ch = 0; ch < 4064; ch += 128) {
    int cn = (4064 - ch >= 128) ? 128 : (4064 - ch);  // 128 or 96 (tail)
    __syncthreads();
    if (col0 < cn) {
      const float* sa = Aq + (size_t)row * Rred + r0 + ch + col0;
      const float* sw = Wf + (size_t)(ot * 32 + row) * Rred + r0 + ch + col0;
#pragma unroll
      for (int q = 0; q < 4; ++q) {
        float4 va = *reinterpret_cast<const float4*>(sa + q * 4);
        *reinterpret_cast<float4*>(&As[row][col0 + q * 4]) = va;
        float4 vw = *reinterpret_cast<const float4*>(sw + q * 4);
        vw.x = q88(vw.x); vw.y = q88(vw.y); vw.z = q88(vw.z); vw.w = q88(vw.w);
        *reinterpret_cast<float4*>(&Ws[row][col0 + q * 4]) = vw;
      }
    }
    __syncthreads();
    int n4 = cn >> 2;
    for (int r4 = 0; r4 < n4; ++r4) {
      float4 av = *reinterpret_cast<const float4*>(&As[tb][r4 * 4]);
#pragma unroll
      for (int i = 0; i < 4; ++i) {
        float4 wv = *reinterpret_cast<const float4*>(&Ws[to + 8 * i][r4 * 4]);
        acc[i] = fmaf(av.x, wv.x, acc[i]);
        acc[i] = fmaf(av.y, wv.y, acc[i]);
        acc[i] = fmaf(av.z, wv.z, acc[i]);
        acc[i] = fmaf(av.w, wv.w, acc[i]);
      }
    }
  }
#pragma unroll
  for (int i = 0; i < 4; ++i) {
    int o = ot * 32 + to + 8 * i;
    partF[((size_t)rs * 32 + tb) * 3072 + o] = acc[i];
  }
}

// ---------------- K10: combine r-partials -> y_feat (q88) -> head conv1x1 --------------------
__global__ __launch_bounds__(256) void k_head(const float* __restrict__ partF, const float* __restrict__ bqf,
                                              const float* __restrict__ wqh, const float* __restrict__ bqh,
                                              float* __restrict__ out) {
  int b = blockIdx.x;
  int tid = threadIdx.x;
  __shared__ float yf[3072];
#pragma unroll
  for (int i = 0; i < 12; ++i) {
    int o = tid + 256 * i;
    float s = bqf[o];
    for (int rsq = 0; rsq < 4; ++rsq) s += partF[((size_t)rsq * 32 + b) * 3072 + o];
    yf[o] = q88(s);
  }
  __syncthreads();
  if (tid < 48) {
    int oh = tid / 24, f = tid % 24;
    float acc = bqh[oh];
    for (int d = 0; d < 128; ++d) acc = fmaf(yf[d * 24 + f], wqh[oh * 128 + d], acc);
    out[(size_t)b * 48 + oh * 24 + f] = q88(acc);
  }
}

}  // namespace

extern "C" void kernel_launch(void* const* d_in, const int* in_sizes, int n_in,
                              void* d_out, int out_size, void* d_ws, size_t ws_size,
                              hipStream_t stream) {
  const float* x      = (const float*)d_in[0];
  const float* wproj  = (const float*)d_in[1];
  const float* bproj  = (const float*)d_in[2];
  const float* wpatch = (const float*)d_in[3];
  const float* bpatch = (const float*)d_in[4];
  const float* pe     = (const float*)d_in[5];
  const float* pescal = (const float*)d_in[6];
  const float* lng    = (const float*)d_in[7];
  const float* lnb    = (const float*)d_in[8];
  const float* win    = (const float*)d_in[9];
  const float* wgate  = (const float*)d_in[10];
  const float* wout   = (const float*)d_in[11];
  const float* wdt    = (const float*)d_in[12];
  const float* bdt    = (const float*)d_in[13];
  const float* lnfg   = (const float*)d_in[14];
  const float* lnfb   = (const float*)d_in[15];
  const float* wflat  = (const float*)d_in[16];
  const float* bflat  = (const float*)d_in[17];
  const float* whead  = (const float*)d_in[18];
  const float* bhead  = (const float*)d_in[19];
  float* out = (float*)d_out;
  float* ws  = (float*)d_ws;

  // ws layout (float offsets)
  constexpr size_t O_WQPROJ  = 0;         // 1024
  constexpr size_t O_BQPROJ  = 1024;      // 128
  constexpr size_t O_WPQ     = 2048;      // 262144   [j][c][d]
  constexpr size_t O_BQPATCH = 264192;    // 128
  constexpr size_t O_WQHEAD  = 264320;    // 256
  constexpr size_t O_BQHEAD  = 264576;    // 2 (pad 128)
  constexpr size_t O_BQFLAT  = 264704;    // 3072
  constexpr size_t O_XPQ     = 267776;    // 4194304  [b][l][c]
  constexpr size_t O_PARTJ   = 4462080;   // 4*520192
  constexpr size_t O_H       = 6542848;   // 520192   [b][k][d]
  constexpr size_t O_U       = 7063040;   // 520192
  constexpr size_t O_G       = 7583232;   // 520192
  constexpr size_t O_LAMP    = 8103424;   // 520192   lam, then p = y*g
  constexpr size_t O_XP2Q    = 8623616;   // 520192   [b][d][k]
  constexpr size_t O_PARTF   = 9143808;   // 4*98304

  k_quant<<<(262144 + 4610 + 255) / 256, 256, 0, stream>>>(
      wproj, bproj, wpatch, bpatch, whead, bhead, bflat,
      ws + O_WQPROJ, ws + O_BQPROJ, ws + O_WPQ, ws + O_BQPATCH,
      ws + O_WQHEAD, ws + O_BQHEAD, ws + O_BQFLAT);

  k_proj<<<2048, 256, 0, stream>>>(x, ws + O_WQPROJ, ws + O_BQPROJ, ws + O_XPQ);

  {
    dim3 g(127, 4);
    k_patch<<<g, 256, 0, stream>>>(ws + O_XPQ, ws + O_WPQ, ws + O_PARTJ);
  }
  k_combine<<<2032, 256, 0, stream>>>(ws + O_PARTJ, ws + O_BQPATCH, pe, pescal, ws + O_H);

  for (int i = 0; i < 4; ++i) {
    dim3 g4(127, 2);
    k_ln_ug<<<g4, 256, 0, stream>>>(ws + O_H, lng + i * 128, lnb + i * 128,
                                    win + (size_t)i * 16384, wgate + (size_t)i * 16384,
                                    ws + O_U, ws + O_G);
    k_lam<<<4064, 128, 0, stream>>>(ws + O_U, wdt + (size_t)i * 16129, bdt + (size_t)i * 127,
                                    ws + O_LAMP);
    k_scan<<<16, 256, 0, stream>>>(ws + O_U, ws + O_G, ws + O_LAMP);
    k_outproj<<<127, 256, 0, stream>>>(ws + O_LAMP, wout + (size_t)i * 16384, ws + O_H);
  }

  k_lnf<<<4064, 128, 0, stream>>>(ws + O_H, lnfg, lnfb, ws + O_XP2Q);

  {
    dim3 g(96, 4);
    k_flat<<<g, 256, 0, stream>>>(ws + O_XP2Q, wflat, ws + O_PARTF);
  }
  k_head<<<32, 256, 0, stream>>>(ws + O_PARTF, ws + O_BQFLAT, ws + O_WQHEAD, ws + O_BQHEAD, out);
}

// Round 2
// 449.600 us; speedup vs baseline: 1.1230x; 1.1230x over previous
//
#include <hip/hip_runtime.h>
#include <cmath>

#define DEV __device__ __forceinline__

namespace {

constexpr int Kp    = 127;          // patch tokens
constexpr int Mrows = 32 * Kp;      // 4064 = B*K
constexpr int Rred  = 128 * Kp;     // 16256 = D*K (flat reduction length)

DEV float q88(float x) {
  float r = rintf(x * 256.0f);                       // round half to even, like jnp.round
  r = fminf(fmaxf(r, -32768.0f), 32767.0f);
  return r * 0.00390625f;
}
DEV float sigmoid_(float x) { return 1.0f / (1.0f + expf(-x)); }

DEV void fma16(const float4 av, const float4 bv, float (&acc)[4][4]) {
  acc[0][0] = fmaf(av.x, bv.x, acc[0][0]); acc[0][1] = fmaf(av.x, bv.y, acc[0][1]);
  acc[0][2] = fmaf(av.x, bv.z, acc[0][2]); acc[0][3] = fmaf(av.x, bv.w, acc[0][3]);
  acc[1][0] = fmaf(av.y, bv.x, acc[1][0]); acc[1][1] = fmaf(av.y, bv.y, acc[1][1]);
  acc[1][2] = fmaf(av.y, bv.z, acc[1][2]); acc[1][3] = fmaf(av.y, bv.w, acc[1][3]);
  acc[2][0] = fmaf(av.z, bv.x, acc[2][0]); acc[2][1] = fmaf(av.z, bv.y, acc[2][1]);
  acc[2][2] = fmaf(av.z, bv.z, acc[2][2]); acc[2][3] = fmaf(av.z, bv.w, acc[2][3]);
  acc[3][0] = fmaf(av.w, bv.x, acc[3][0]); acc[3][1] = fmaf(av.w, bv.y, acc[3][1]);
  acc[3][2] = fmaf(av.w, bv.z, acc[3][2]); acc[3][3] = fmaf(av.w, bv.w, acc[3][3]);
}

// ---------------- K0: quantize small weights (and transpose w_patch to [j][c][d]) -------------
__global__ __launch_bounds__(256) void k_quant(
    const float* __restrict__ wproj, const float* __restrict__ bproj,
    const float* __restrict__ wpatch, const float* __restrict__ bpatch,
    const float* __restrict__ whead, const float* __restrict__ bhead,
    const float* __restrict__ bflat,
    float* __restrict__ wq_proj, float* __restrict__ bq_proj, float* __restrict__ wpq,
    float* __restrict__ bq_patch, float* __restrict__ wq_head, float* __restrict__ bq_head,
    float* __restrict__ bq_flat) {
  int i = blockIdx.x * 256 + threadIdx.x;
  if (i < 262144) {
    int j = i >> 14;          // /16384
    int c = (i >> 7) & 127;
    int d = i & 127;
    wpq[i] = q88(wpatch[(d * 128 + c) * 16 + j]);   // w_patch[d][c][j] -> wpq[j][c][d]
  }
  int t = i - 262144;
  if (t >= 0) {
    if      (t < 1024) wq_proj[t]         = q88(wproj[t]);
    else if (t < 1152) bq_proj[t - 1024]  = q88(bproj[t - 1024]);
    else if (t < 1280) bq_patch[t - 1152] = q88(bpatch[t - 1152]);
    else if (t < 1536) wq_head[t - 1280]  = q88(whead[t - 1280]);
    else if (t < 1538) bq_head[t - 1536]  = q88(bhead[t - 1536]);
    else if (t < 4610) bq_flat[t - 1538]  = q88(bflat[t - 1538]);
  }
}

// ---------------- K1: 1x1 conv (proj) -> xpq[b][l][c] (quantized) ----------------------------
__global__ __launch_bounds__(256) void k_proj(const float* __restrict__ x, const float* __restrict__ wq,
                                              const float* __restrict__ bq, float* __restrict__ xpq) {
  int bl0 = blockIdx.x * 16;          // 16 (b,l) rows per block; grid 2048
  int tid = threadIdx.x;
  __shared__ float xs[128];
  if (tid < 128) xs[tid] = q88(x[(size_t)bl0 * 8 + tid]);
  __syncthreads();
  int o = tid & 127;
  int half = tid >> 7;                // 0,1
  float wv[8];
#pragma unroll
  for (int c = 0; c < 8; ++c) wv[c] = wq[o * 8 + c];
  float bb = bq[o];
#pragma unroll
  for (int il = 0; il < 8; ++il) {
    int l_loc = half * 8 + il;
    float acc = bb;
#pragma unroll
    for (int c = 0; c < 8; ++c) acc = fmaf(xs[l_loc * 8 + c], wv[c], acc);
    xpq[(size_t)(bl0 + l_loc) * 128 + o] = q88(acc);
  }
}

// ---------------- K2: patch conv as 16 accumulated GEMMs, j-split x4 -------------------------
__global__ __launch_bounds__(256) void k_patch(const float* __restrict__ xpq, const float* __restrict__ wpq,
                                               float* __restrict__ partJ) {
  __shared__ __align__(16) float As[128][36];
  int mt = blockIdx.x, jg = blockIdx.y;
  int tid = threadIdx.x;
  int mr = tid & 31, c0 = (tid >> 5) * 16;
  int tn = tid & 31, tm8 = tid >> 5;
  int m0 = mt * 32;
  int g = m0 + mr;
  int bb = g / 127, kq = g % 127;
  float acc[4][4] = {};
  for (int jj = 0; jj < 4; ++jj) {
    int j = jg * 4 + jj;
    const float* src = xpq + ((size_t)bb * 1024 + kq * 8 + j) * 128 + c0;
    __syncthreads();
#pragma unroll
    for (int q = 0; q < 4; ++q) {
      float4 v = *reinterpret_cast<const float4*>(src + q * 4);
      As[c0 + q * 4 + 0][mr] = v.x;
      As[c0 + q * 4 + 1][mr] = v.y;
      As[c0 + q * 4 + 2][mr] = v.z;
      As[c0 + q * 4 + 3][mr] = v.w;
    }
    __syncthreads();
    const float* wp = wpq + (size_t)j * 16384 + tn * 4;
#pragma unroll 4
    for (int c = 0; c < 128; ++c) {
      float4 bv = *reinterpret_cast<const float4*>(wp + c * 128);
      float4 av = *reinterpret_cast<const float4*>(&As[c][tm8 * 4]);
      fma16(av, bv, acc);
    }
  }
  float* dst = partJ + ((size_t)jg * Mrows + m0) * 128 + tn * 4;
#pragma unroll
  for (int i = 0; i < 4; ++i) {
    float4 o4 = make_float4(acc[i][0], acc[i][1], acc[i][2], acc[i][3]);
    *reinterpret_cast<float4*>(dst + (size_t)(tm8 * 4 + i) * 128) = o4;
  }
}

// ---------------- K3: combine j-partials + bias, q88, add positional encoding ----------------
__global__ __launch_bounds__(256) void k_combine(const float* __restrict__ partJ, const float* __restrict__ bqp,
                                                 const float* __restrict__ pe, const float* __restrict__ pesc,
                                                 float* __restrict__ h) {
  int i = blockIdx.x * 256 + threadIdx.x;  // < 520192
  int n = i & 127;
  int gq = i >> 7;
  int k = gq % 127;
  float s = partJ[i] + partJ[520192 + i] + partJ[2 * 520192 + i] + partJ[3 * 520192 + i] + bqp[n];
  h[i] = q88(s) + pesc[0] * pe[k * 128 + n];
}

// ---------------- K4: layernorm + (hn @ w_in -> silu -> u) / (hn @ w_gate -> silu -> g) -------
__global__ __launch_bounds__(256) void k_ln_ug(const float* __restrict__ h, const float* __restrict__ lng,
                                               const float* __restrict__ lnb, const float* __restrict__ Win,
                                               const float* __restrict__ Wgate, float* __restrict__ u,
                                               float* __restrict__ gbuf) {
  __shared__ __align__(16) float As[128][36];
  __shared__ float2 lnpart[8][32];
  __shared__ float mean_s[32], inv_s[32];
  const float* W = blockIdx.y ? Wgate : Win;
  float* out = blockIdx.y ? gbuf : u;
  int tid = threadIdx.x;
  int mr = tid & 31, c0 = (tid >> 5) * 16;
  int m0 = blockIdx.x * 32;
  const float* src = h + (size_t)(m0 + mr) * 128 + c0;
  float s1 = 0.f, s2 = 0.f;
#pragma unroll
  for (int q = 0; q < 4; ++q) {
    float4 v = *reinterpret_cast<const float4*>(src + q * 4);
    As[c0 + q * 4 + 0][mr] = v.x;
    As[c0 + q * 4 + 1][mr] = v.y;
    As[c0 + q * 4 + 2][mr] = v.z;
    As[c0 + q * 4 + 3][mr] = v.w;
    s1 += v.x + v.y + v.z + v.w;
    s2 = fmaf(v.x, v.x, s2); s2 = fmaf(v.y, v.y, s2);
    s2 = fmaf(v.z, v.z, s2); s2 = fmaf(v.w, v.w, s2);
  }
  lnpart[tid >> 5][mr] = make_float2(s1, s2);
  __syncthreads();
  if (tid < 32) {
    float s = 0.f, ss = 0.f;
#pragma unroll
    for (int j = 0; j < 8; ++j) { float2 p = lnpart[j][tid]; s += p.x; ss += p.y; }
    float mn = s * (1.0f / 128.0f);
    float var = ss * (1.0f / 128.0f) - mn * mn;
    mean_s[tid] = mn;
    inv_s[tid] = rsqrtf(var + 1e-5f);
  }
  __syncthreads();
  float mnv = mean_s[mr], invv = inv_s[mr];
#pragma unroll
  for (int q = 0; q < 16; ++q) {
    int c = c0 + q;
    As[c][mr] = (As[c][mr] - mnv) * invv * lng[c] + lnb[c];
  }
  __syncthreads();
  int tn = tid & 31, tm8 = tid >> 5;
  float acc[4][4] = {};
  const float* wp = W + tn * 4;
#pragma unroll 4
  for (int c = 0; c < 128; ++c) {
    float4 bv = *reinterpret_cast<const float4*>(wp + c * 128);
    float4 av = *reinterpret_cast<const float4*>(&As[c][tm8 * 4]);
    fma16(av, bv, acc);
  }
  float* dst = out + (size_t)m0 * 128 + tn * 4;
#pragma unroll
  for (int i = 0; i < 4; ++i) {
    float4 o4;
    { float xq = q88(acc[i][0]); o4.x = q88(xq * sigmoid_(xq)); }
    { float xq = q88(acc[i][1]); o4.y = q88(xq * sigmoid_(xq)); }
    { float xq = q88(acc[i][2]); o4.z = q88(xq * sigmoid_(xq)); }
    { float xq = q88(acc[i][3]); o4.w = q88(xq * sigmoid_(xq)); }
    *reinterpret_cast<float4*>(dst + (size_t)(tm8 * 4 + i) * 128) = o4;
  }
}

// ---------------- K5: lambda = q88(sigmoid(q88(u @ w_dt^T + b_dt))) --------------------------
__global__ __launch_bounds__(128) void k_lam(const float* __restrict__ u, const float* __restrict__ wdt,
                                             const float* __restrict__ bdt, float* __restrict__ lam) {
  int blk = blockIdx.x;
  int b = blk / 127, t = blk % 127;
  int d = threadIdx.x;
  __shared__ float wr[127];
  if (d < 127) wr[d] = wdt[t * 127 + d];
  __syncthreads();
  const float* up = u + (size_t)b * (127 * 128) + d;
  float acc = 0.f;
#pragma unroll 4
  for (int k = 0; k < 127; ++k) acc = fmaf(up[(size_t)k * 128], wr[k], acc);
  float pre = q88(acc + bdt[t]);
  lam[((size_t)b * 127 + t) * 128 + d] = q88(sigmoid_(pre));
}

// ---------------- K6: sequential scan, fused with p = y*g (in-place over lam buffer) ---------
__global__ __launch_bounds__(256) void k_scan(const float* __restrict__ u, const float* __restrict__ gbuf,
                                              float* __restrict__ lamp) {
  int gt = blockIdx.x * 256 + threadIdx.x;  // 4096 = B*D
  int b = gt >> 7, d = gt & 127;
  size_t base = (size_t)b * (127 * 128) + d;
  float s = 0.f;
  for (int t = 0; t < 127; ++t) {
    size_t idx = base + (size_t)t * 128;
    float lm = lamp[idx];
    float uu = u[idx];
    s = lm * s + (1.0f - lm) * uu;
    lamp[idx] = s * gbuf[idx];
  }
}

// ---------------- K7: h += p @ w_out --------------------------------------------------------
__global__ __launch_bounds__(256) void k_outproj(const float* __restrict__ p, const float* __restrict__ W,
                                                 float* __restrict__ h) {
  __shared__ __align__(16) float As[128][36];
  int tid = threadIdx.x;
  int mr = tid & 31, c0 = (tid >> 5) * 16;
  int m0 = blockIdx.x * 32;
  const float* src = p + (size_t)(m0 + mr) * 128 + c0;
#pragma unroll
  for (int q = 0; q < 4; ++q) {
    float4 v = *reinterpret_cast<const float4*>(src + q * 4);
    As[c0 + q * 4 + 0][mr] = v.x;
    As[c0 + q * 4 + 1][mr] = v.y;
    As[c0 + q * 4 + 2][mr] = v.z;
    As[c0 + q * 4 + 3][mr] = v.w;
  }
  __syncthreads();
  int tn = tid & 31, tm8 = tid >> 5;
  float acc[4][4] = {};
  const float* wp = W + tn * 4;
#pragma unroll 4
  for (int c = 0; c < 128; ++c) {
    float4 bv = *reinterpret_cast<const float4*>(wp + c * 128);
    float4 av = *reinterpret_cast<const float4*>(&As[c][tm8 * 4]);
    fma16(av, bv, acc);
  }
  float* dst = h + (size_t)m0 * 128 + tn * 4;
#pragma unroll
  for (int i = 0; i < 4; ++i) {
    float4 hv = *reinterpret_cast<float4*>(dst + (size_t)(tm8 * 4 + i) * 128);
    hv.x += acc[i][0]; hv.y += acc[i][1]; hv.z += acc[i][2]; hv.w += acc[i][3];
    *reinterpret_cast<float4*>(dst + (size_t)(tm8 * 4 + i) * 128) = hv;
  }
}

// ---------------- K8: final layernorm + q88 + (implicit) transpose to [b][r] ----------------
__global__ __launch_bounds__(128) void k_lnf(const float* __restrict__ h, const float* __restrict__ gg,
                                             const float* __restrict__ bb, float* __restrict__ xp2q) {
  int row = blockIdx.x;  // 4064
  int d = threadIdx.x;
  float v = h[(size_t)row * 128 + d];
  __shared__ float red[128];
  __shared__ float mn_s, inv_s;
  red[d] = v;
  __syncthreads();
  for (int off = 64; off > 0; off >>= 1) {
    if (d < off) red[d] += red[d + off];
    __syncthreads();
  }
  if (d == 0) mn_s = red[0] * (1.0f / 128.0f);
  __syncthreads();
  float dv = v - mn_s;
  red[d] = dv * dv;
  __syncthreads();
  for (int off = 64; off > 0; off >>= 1) {
    if (d < off) red[d] += red[d + off];
    __syncthreads();
  }
  if (d == 0) inv_s = rsqrtf(red[0] * (1.0f / 128.0f) + 1e-5f);
  __syncthreads();
  float hn = (v - mn_s) * inv_s * gg[d] + bb[d];
  int b = row / 127, k = row % 127;
  xp2q[((size_t)b * 128 + d) * 127 + k] = q88(hn);
}

// ---------------- K9: flat contraction, register-tiled 8b x 4o, r-split x32 ------------------
// C[b,o] = sum_r Aq[b,r]*q88(Wf[o,r]);  Aq layout [32][16256] (= xp2q [b][d][k])
// grid (24 o-tiles x 32 r-splits), 128 threads (2 waves), thread tile 8b x 4o.
__global__ __launch_bounds__(128) void k_flat(const float* __restrict__ Aq, const float* __restrict__ Wf,
                                              float* __restrict__ partF) {
  constexpr int RC = 32;                       // r per LDS chunk
  __shared__ __align__(16) float As[RC][36];   // [r][b]
  __shared__ __align__(16) float Ws[RC][132];  // [r][o]
  int ot = blockIdx.x, rs = blockIdx.y;
  int tid = threadIdx.x;
  int og = tid & 31;        // 32 o-groups of 4
  int bg = tid >> 5;        // 4 b-groups of 8
  int o0 = ot * 128;
  int r0 = rs * 512;        // virtual R padded to 16384
  float acc[8][4] = {};
  for (int ch = 0; ch < 512; ch += RC) {
    int rbase = r0 + ch;
    __syncthreads();
    // stage A: RC r x 32 b   (reads [b][r] global, writes [r][b] LDS)
    {
      int r = tid & 31;
      int b = tid >> 5;                     // +4 per pass
      int rr = rbase + r;
      bool ok = rr < Rred;
#pragma unroll
      for (int q = 0; q < 8; ++q) {
        int bb2 = b + 4 * q;
        As[r][bb2] = ok ? Aq[(size_t)bb2 * Rred + rr] : 0.f;
      }
    }
    // stage W: RC r x 128 o, q88 on load   (reads [o][r] global, writes [r][o] LDS)
    {
      int r = tid & 31;
      int oo = tid >> 5;                    // +4 per pass
      int rr = rbase + r;
      size_t rcl = (rr < Rred) ? (size_t)rr : (size_t)(Rred - 1);
#pragma unroll 8
      for (int q = 0; q < 32; ++q) {
        int o = oo + 4 * q;
        Ws[r][o] = q88(Wf[(size_t)(o0 + o) * Rred + rcl]);
      }
    }
    __syncthreads();
#pragma unroll 4
    for (int r = 0; r < RC; ++r) {
      float4 w  = *reinterpret_cast<const float4*>(&Ws[r][og * 4]);
      float4 a0 = *reinterpret_cast<const float4*>(&As[r][bg * 8]);
      float4 a1 = *reinterpret_cast<const float4*>(&As[r][bg * 8 + 4]);
      acc[0][0] = fmaf(a0.x, w.x, acc[0][0]); acc[0][1] = fmaf(a0.x, w.y, acc[0][1]);
      acc[0][2] = fmaf(a0.x, w.z, acc[0][2]); acc[0][3] = fmaf(a0.x, w.w, acc[0][3]);
      acc[1][0] = fmaf(a0.y, w.x, acc[1][0]); acc[1][1] = fmaf(a0.y, w.y, acc[1][1]);
      acc[1][2] = fmaf(a0.y, w.z, acc[1][2]); acc[1][3] = fmaf(a0.y, w.w, acc[1][3]);
      acc[2][0] = fmaf(a0.z, w.x, acc[2][0]); acc[2][1] = fmaf(a0.z, w.y, acc[2][1]);
      acc[2][2] = fmaf(a0.z, w.z, acc[2][2]); acc[2][3] = fmaf(a0.z, w.w, acc[2][3]);
      acc[3][0] = fmaf(a0.w, w.x, acc[3][0]); acc[3][1] = fmaf(a0.w, w.y, acc[3][1]);
      acc[3][2] = fmaf(a0.w, w.z, acc[3][2]); acc[3][3] = fmaf(a0.w, w.w, acc[3][3]);
      acc[4][0] = fmaf(a1.x, w.x, acc[4][0]); acc[4][1] = fmaf(a1.x, w.y, acc[4][1]);
      acc[4][2] = fmaf(a1.x, w.z, acc[4][2]); acc[4][3] = fmaf(a1.x, w.w, acc[4][3]);
      acc[5][0] = fmaf(a1.y, w.x, acc[5][0]); acc[5][1] = fmaf(a1.y, w.y, acc[5][1]);
      acc[5][2] = fmaf(a1.y, w.z, acc[5][2]); acc[5][3] = fmaf(a1.y, w.w, acc[5][3]);
      acc[6][0] = fmaf(a1.z, w.x, acc[6][0]); acc[6][1] = fmaf(a1.z, w.y, acc[6][1]);
      acc[6][2] = fmaf(a1.z, w.z, acc[6][2]); acc[6][3] = fmaf(a1.z, w.w, acc[6][3]);
      acc[7][0] = fmaf(a1.w, w.x, acc[7][0]); acc[7][1] = fmaf(a1.w, w.y, acc[7][1]);
      acc[7][2] = fmaf(a1.w, w.z, acc[7][2]); acc[7][3] = fmaf(a1.w, w.w, acc[7][3]);
    }
  }
  // write partF[rs][b][o], b = bg*8 + bi, o = o0 + og*4 + oi  (coalesced float4)
#pragma unroll
  for (int bi = 0; bi < 8; ++bi) {
    int b = bg * 8 + bi;
    float4 o4 = make_float4(acc[bi][0], acc[bi][1], acc[bi][2], acc[bi][3]);
    *reinterpret_cast<float4*>(partF + ((size_t)rs * 32 + b) * 3072 + o0 + og * 4) = o4;
  }
}

// ---------------- K10: combine r-partials -> y_feat (q88) -> head conv1x1 --------------------
__global__ __launch_bounds__(256) void k_head(const float* __restrict__ partF, const float* __restrict__ bqf,
                                              const float* __restrict__ wqh, const float* __restrict__ bqh,
                                              float* __restrict__ out) {
  int b = blockIdx.x;
  int tid = threadIdx.x;
  __shared__ float yf[3072];
#pragma unroll
  for (int i = 0; i < 12; ++i) {
    int o = tid + 256 * i;
    float s = bqf[o];
    for (int rsq = 0; rsq < 32; ++rsq) s += partF[((size_t)rsq * 32 + b) * 3072 + o];
    yf[o] = q88(s);
  }
  __syncthreads();
  if (tid < 48) {
    int oh = tid / 24, f = tid % 24;
    float acc = bqh[oh];
    for (int d = 0; d < 128; ++d) acc = fmaf(yf[d * 24 + f], wqh[oh * 128 + d], acc);
    out[(size_t)b * 48 + oh * 24 + f] = q88(acc);
  }
}

}  // namespace

extern "C" void kernel_launch(void* const* d_in, const int* in_sizes, int n_in,
                              void* d_out, int out_size, void* d_ws, size_t ws_size,
                              hipStream_t stream) {
  const float* x      = (const float*)d_in[0];
  const float* wproj  = (const float*)d_in[1];
  const float* bproj  = (const float*)d_in[2];
  const float* wpatch = (const float*)d_in[3];
  const float* bpatch = (const float*)d_in[4];
  const float* pe     = (const float*)d_in[5];
  const float* pescal = (const float*)d_in[6];
  const float* lng    = (const float*)d_in[7];
  const float* lnb    = (const float*)d_in[8];
  const float* win    = (const float*)d_in[9];
  const float* wgate  = (const float*)d_in[10];
  const float* wout   = (const float*)d_in[11];
  const float* wdt    = (const float*)d_in[12];
  const float* bdt    = (const float*)d_in[13];
  const float* lnfg   = (const float*)d_in[14];
  const float* lnfb   = (const float*)d_in[15];
  const float* wflat  = (const float*)d_in[16];
  const float* bflat  = (const float*)d_in[17];
  const float* whead  = (const float*)d_in[18];
  const float* bhead  = (const float*)d_in[19];
  float* out = (float*)d_out;
  float* ws  = (float*)d_ws;

  // ws layout (float offsets)
  constexpr size_t O_WQPROJ  = 0;         // 1024
  constexpr size_t O_BQPROJ  = 1024;      // 128
  constexpr size_t O_WPQ     = 2048;      // 262144   [j][c][d]
  constexpr size_t O_BQPATCH = 264192;    // 128
  constexpr size_t O_WQHEAD  = 264320;    // 256
  constexpr size_t O_BQHEAD  = 264576;    // 2 (pad 128)
  constexpr size_t O_BQFLAT  = 264704;    // 3072
  constexpr size_t O_XPQ     = 267776;    // 4194304  [b][l][c]; later reused as partF (3145728)
  constexpr size_t O_PARTJ   = 4462080;   // 4*520192
  constexpr size_t O_H       = 6542848;   // 520192   [b][k][d]
  constexpr size_t O_U       = 7063040;   // 520192
  constexpr size_t O_G       = 7583232;   // 520192
  constexpr size_t O_LAMP    = 8103424;   // 520192   lam, then p = y*g
  constexpr size_t O_XP2Q    = 8623616;   // 520192   [b][r] (= [b][d][k])
  constexpr size_t O_PARTF   = O_XPQ;     // 32*32*3072 reuse (xpq dead after k_patch)

  k_quant<<<(262144 + 4610 + 255) / 256, 256, 0, stream>>>(
      wproj, bproj, wpatch, bpatch, whead, bhead, bflat,
      ws + O_WQPROJ, ws + O_BQPROJ, ws + O_WPQ, ws + O_BQPATCH,
      ws + O_WQHEAD, ws + O_BQHEAD, ws + O_BQFLAT);

  k_proj<<<2048, 256, 0, stream>>>(x, ws + O_WQPROJ, ws + O_BQPROJ, ws + O_XPQ);

  {
    dim3 g(127, 4);
    k_patch<<<g, 256, 0, stream>>>(ws + O_XPQ, ws + O_WPQ, ws + O_PARTJ);
  }
  k_combine<<<2032, 256, 0, stream>>>(ws + O_PARTJ, ws + O_BQPATCH, pe, pescal, ws + O_H);

  for (int i = 0; i < 4; ++i) {
    dim3 g4(127, 2);
    k_ln_ug<<<g4, 256, 0, stream>>>(ws + O_H, lng + i * 128, lnb + i * 128,
                                    win + (size_t)i * 16384, wgate + (size_t)i * 16384,
                                    ws + O_U, ws + O_G);
    k_lam<<<4064, 128, 0, stream>>>(ws + O_U, wdt + (size_t)i * 16129, bdt + (size_t)i * 127,
                                    ws + O_LAMP);
    k_scan<<<16, 256, 0, stream>>>(ws + O_U, ws + O_G, ws + O_LAMP);
    k_outproj<<<127, 256, 0, stream>>>(ws + O_LAMP, wout + (size_t)i * 16384, ws + O_H);
  }

  k_lnf<<<4064, 128, 0, stream>>>(ws + O_H, lnfg, lnfb, ws + O_XP2Q);

  {
    dim3 g(24, 32);
    k_flat<<<g, 128, 0, stream>>>(ws + O_XP2Q, wflat, ws + O_PARTF);
  }
  k_head<<<32, 256, 0, stream>>>(ws + O_PARTF, ws + O_BQFLAT, ws + O_WQHEAD, ws + O_BQHEAD, out);
}